// Round 6
// baseline (515.212 us; speedup 1.0000x reference)
//
#include <hip/hip_runtime.h>
#include <math.h>

#define N_TOK 32768
#define DIM   256
#define KCODE 4096

// ---- workspace layout (float offsets) ----
#define WS_E2      0                      // [4096]
#define WS_COUNTS  4096                   // [4096]
#define WS_LOSSP   8192                   // [256]
#define WS_SCAL    8448                   // [64]  scal[0]=bias
#define WS_CNORM   8512                   // [4096]
#define WS_IDX     12608                  // int [32768]
#define WS_EHS     307520                 // fp16 planes [2][16][8][256][32] = 4 MB
#define WS_DWT     1356096                // dwT [4096*256]
#define WS_CARRYV  2404672                // float [32768] carry best value / later rowlist
#define WS_CARRYI  2437440                // int   [32768] carry best index
#define WS_OFFS    2470208                // int [4096] bucket starts
#define WS_WOFF    2474304                // int [4096] scatter cursors

// ---- output layout (float offsets) ----
#define OUT_Q      0
#define OUT_LOSS   8388608
#define OUT_PERP   8388609
#define OUT_IDX    8388610
#define OUT_EMB    8421378

#define EH_PLANE   1048576                // halves per eh plane
#define XH_PLANE   8388608                // halves per xh plane

typedef _Float16 f16x8 __attribute__((ext_vector_type(8)));
typedef _Float16 f16x4 __attribute__((ext_vector_type(4)));
typedef float    f32x4 __attribute__((ext_vector_type(4)));

// ||e_k||^2, partials over d with atomics (e2 pre-zeroed)
__global__ void k_e2(const float* __restrict__ emb, float* __restrict__ e2)
{
    int k  = blockIdx.x * 256 + threadIdx.x;
    int d0 = blockIdx.y * 32;
    float s = 0.0f;
#pragma unroll 8
    for (int d = 0; d < 32; ++d) {
        float v = emb[(size_t)(d0 + d) * KCODE + k];
        s += v * v;
    }
    atomicAdd(&e2[k], s);
}

// x [N][D] -> split fp16 planes xh[2][N][D] (stored in d_out OUT_Q region)
__global__ void k_split_x(const float* __restrict__ x, unsigned short* __restrict__ xh)
{
    int i = (blockIdx.x * 256 + threadIdx.x) * 8;
    float4 f0 = *(const float4*)(x + i);
    float4 f1 = *(const float4*)(x + i + 4);
    float fv[8] = {f0.x, f0.y, f0.z, f0.w, f1.x, f1.y, f1.z, f1.w};
    f16x8 h1, h2;
#pragma unroll
    for (int j = 0; j < 8; ++j) {
        _Float16 a = (_Float16)fv[j];
        h1[j] = a;
        h2[j] = (_Float16)(fv[j] - (float)a);
    }
    *(f16x8*)((_Float16*)xh + i)            = h1;
    *(f16x8*)((_Float16*)xh + XH_PLANE + i) = h2;
}

// emb [D][K] -> pre-tiled split planes ehs[p][ct][ks][code&255][d&31]
__global__ void k_split_e(const float* __restrict__ emb, unsigned short* __restrict__ ehs_)
{
    __shared__ float tile[32][33];
    _Float16* ehs = (_Float16*)ehs_;
    int t  = threadIdx.x;
    int tx = t & 31, iy = t >> 5;
    int k0 = blockIdx.x * 32, d0 = blockIdx.y * 32;
#pragma unroll
    for (int j = 0; j < 4; ++j)
        tile[iy + 8 * j][tx] = emb[(size_t)(d0 + iy + 8 * j) * KCODE + k0 + tx];
    __syncthreads();
    int code = k0 + tx;
    size_t base = (size_t)(((code >> 8) * 8) + (d0 >> 5)) * 8192 + (code & 255) * 32 + iy * 4;
    f16x4 h1, h2;
#pragma unroll
    for (int j = 0; j < 4; ++j) {
        float v = tile[iy * 4 + j][tx];
        _Float16 a = (_Float16)v;
        h1[j] = a;
        h2[j] = (_Float16)(v - (float)a);
    }
    *(f16x4*)(ehs + base)            = h1;
    *(f16x4*)(ehs + EH_PLANE + base) = h2;
}

// Argmin over codes via fp16x2-split MFMA, two ct-half dispatches (2 MB L2 WS each).
// Geometry: 64-row blocks (Ah = 64 KB, 2 blocks/CU, 2 waves/SIMD). This is the
// L2-safe config: per-CU B demand ~35 B/cyc (round 5's 32-row blocks doubled it
// to ~70 B/cyc and hit the per-XCD L2 BW wall -> 28% MfmaUtil).
// MFMA order: nf-grouped product-major — per nf issue a2b1(mf0..3), a1b2(mf0..3),
// a1b1(mf0..3): same-accumulator reuse distance 4 (~78 cyc) > MFMA latency, so a
// wave's in-order stream has no dep stalls (round 3's per-acc 3-chains did).
__global__ __launch_bounds__(256, 2)
void k_argmin(const unsigned short* __restrict__ xh_, const unsigned short* __restrict__ ehs_,
              const float* __restrict__ e2, int* __restrict__ idx_out,
              float* __restrict__ carryV, int* __restrict__ carryI,
              float* __restrict__ out_idxf, float* __restrict__ counts,
              int ct0, int phase)
{
    __shared__ __align__(16) _Float16 Ah[2][64][256];   // 64 KB; XOR-swizzled 8-elem groups

    const _Float16* xh  = (const _Float16*)xh_;
    const _Float16* ehs = (const _Float16*)ehs_;

    const int t    = threadIdx.x;
    const int lane = t & 63, w = t >> 6;
    const int lo   = lane & 15, q = lane >> 4;
    const int row0 = blockIdx.x * 64;

    // ---- prologue: stage A planes from xh (rows m and m+32), non-temporal ----
    {
        int m = t >> 3, kb = (t & 7) * 32;
#pragma unroll
        for (int p = 0; p < 2; ++p)
#pragma unroll
            for (int rr = 0; rr < 2; ++rr) {
                int mm = m + 32 * rr;
                const _Float16* src = xh + (size_t)p * XH_PLANE + (size_t)(row0 + mm) * DIM + kb;
#pragma unroll
                for (int g = 0; g < 4; ++g) {
                    f16x8 h = __builtin_nontemporal_load((const f16x8*)(src + g * 8));
                    int grp = ((kb >> 3) + g) ^ (mm & 7);
                    *(f16x8*)&Ah[p][mm][grp * 8] = h;
                }
            }
    }
    __syncthreads();   // the ONLY barrier before the epilogue

    float best[16];
    int   bidx[16];
#pragma unroll
    for (int s = 0; s < 16; ++s) { best[s] = 3.4e38f; bidx[s] = 0; }

    // B fragment base: code-within-tile crow = w*64 + nf*16 + lo, d-off q*8
    const _Float16* ehp1 = ehs + (size_t)(w * 64 + lo) * 32 + q * 8;
    const _Float16* ehp2 = ehp1 + EH_PLANE;

    for (int ct = ct0; ct < ct0 + 8; ++ct) {
        f32x4 acc[4][4];
#pragma unroll
        for (int mf = 0; mf < 4; ++mf)
#pragma unroll
            for (int nf = 0; nf < 4; ++nf) acc[mf][nf] = (f32x4)0.0f;

#pragma unroll
        for (int ks = 0; ks < 8; ++ks) {
            const size_t so = (size_t)(ct * 8 + ks) * 8192;

            // B fragments (single-buffered; compiler pipelines across unrolled ks)
            f16x8 b1[4], b2[4];
#pragma unroll
            for (int nf = 0; nf < 4; ++nf) {
                b1[nf] = *(const f16x8*)(ehp1 + so + nf * 512);
                b2[nf] = *(const f16x8*)(ehp2 + so + nf * 512);
            }

            // A fragments via LDS (conflict-free b128 via XOR swizzle)
            const int agrp = ((ks * 4 + q) ^ (lo & 7)) * 8;
            f16x8 a1[4], a2[4];
#pragma unroll
            for (int mf = 0; mf < 4; ++mf) {
                a2[mf] = *(const f16x8*)&Ah[1][mf * 16 + lo][agrp];
                a1[mf] = *(const f16x8*)&Ah[0][mf * 16 + lo][agrp];
            }

            // nf-grouped product-major: acc reuse distance 4 -> no MFMA dep stalls,
            // B liveness stays at 8 fragments.
            __builtin_amdgcn_s_setprio(1);
#pragma unroll
            for (int nf = 0; nf < 4; ++nf) {
#pragma unroll
                for (int mf = 0; mf < 4; ++mf)
                    acc[mf][nf] = __builtin_amdgcn_mfma_f32_16x16x32_f16(a2[mf], b1[nf], acc[mf][nf], 0, 0, 0);
#pragma unroll
                for (int mf = 0; mf < 4; ++mf)
                    acc[mf][nf] = __builtin_amdgcn_mfma_f32_16x16x32_f16(a1[mf], b2[nf], acc[mf][nf], 0, 0, 0);
#pragma unroll
                for (int mf = 0; mf < 4; ++mf)
                    acc[mf][nf] = __builtin_amdgcn_mfma_f32_16x16x32_f16(a1[mf], b1[nf], acc[mf][nf], 0, 0, 0);
            }
            __builtin_amdgcn_s_setprio(0);
        }

        // fold: dist = e2 - 2*score (x^2 row-constant dropped). codes ascending in ct,nf.
#pragma unroll
        for (int nf = 0; nf < 4; ++nf) {
            int cl = w * 64 + nf * 16 + lo;
            float e2v = e2[ct * 256 + cl];
#pragma unroll
            for (int mf = 0; mf < 4; ++mf)
#pragma unroll
                for (int r = 0; r < 4; ++r) {
                    float dist = fmaf(-2.0f, acc[mf][nf][r], e2v);
                    int s = mf * 4 + r;
                    if (dist < best[s]) { best[s] = dist; bidx[s] = ct * 256 + cl; }
                }
        }
    }

    // ---- final argmin reduction (scratch overlays Ah) ----
    __syncthreads();
    float* rv = (float*)&Ah[0][0][0];                 // [64 rows][64 slots]
    int*   ri = (int*)(((char*)&Ah[0][0][0]) + 16384);
#pragma unroll
    for (int s = 0; s < 16; ++s) {
        int row = (s >> 2) * 16 + q * 4 + (s & 3);    // mf*16 + q*4 + r
        rv[row * 64 + w * 16 + lo] = best[s];
        ri[row * 64 + w * 16 + lo] = bidx[s];
    }
    __syncthreads();
    if (t < 64) {
        float bv; int bi;
        if (phase) { bv = carryV[row0 + t]; bi = carryI[row0 + t]; }
        else       { bv = 3.4e38f; bi = 0x40000000; }
        // staggered scan -> conflict-free
        for (int jj = 0; jj < 64; ++jj) {
            int j = (jj + t) & 63;
            float v = rv[t * 64 + j];
            int  ii = ri[t * 64 + j];
            if (v < bv || (v == bv && ii < bi)) { bv = v; bi = ii; }
        }
        if (phase) {
            idx_out[row0 + t] = bi;
            out_idxf[row0 + t] = (float)bi;
            atomicAdd(&counts[bi], 1.0f);
        } else {
            carryV[row0 + t] = bv; carryI[row0 + t] = bi;
        }
    }
}

// exclusive prefix sum over counts[4096] -> offs, woff (one block, 256 threads x 16)
__global__ void k_scan(const float* __restrict__ counts, int* __restrict__ offs,
                       int* __restrict__ woff)
{
    __shared__ int ps[256];
    int t = threadIdx.x;
    int local[16];
    int s = 0;
#pragma unroll
    for (int j = 0; j < 16; ++j) {
        local[j] = s;
        s += (int)counts[t * 16 + j];
    }
    ps[t] = s;
    __syncthreads();
    for (int off = 1; off < 256; off <<= 1) {
        int v = (t >= off) ? ps[t - off] : 0;
        __syncthreads();
        ps[t] += v;
        __syncthreads();
    }
    int base = (t > 0) ? ps[t - 1] : 0;
#pragma unroll
    for (int j = 0; j < 16; ++j) {
        int o = base + local[j];
        offs[t * 16 + j] = o;
        woff[t * 16 + j] = o;
    }
}

// rowlist[pos] = n, grouped by code (counting-sort scatter)
__global__ void k_scatter(const int* __restrict__ idx, int* __restrict__ woff,
                          int* __restrict__ rowlist)
{
    int n = blockIdx.x * 256 + threadIdx.x;
    int k = idx[n];
    int pos = atomicAdd(&woff[k], 1);
    rowlist[pos] = n;
}

// dwT[k][d] = sum of x rows assigned to code k — one block per code, NO atomics
__global__ void k_dw(const float* __restrict__ x, const int* __restrict__ rowlist,
                     const int* __restrict__ offs, const float* __restrict__ counts,
                     float* __restrict__ dwT)
{
    __shared__ float red[4][256];
    int k = blockIdx.x;
    int t = threadIdx.x;
    int lane = t & 63, w = t >> 6;
    int start = offs[k];
    int cnt   = (int)counts[k];
    float4 acc = {0.0f, 0.0f, 0.0f, 0.0f};
    int j = w;
    for (; j + 4 < cnt; j += 8) {
        int n0 = rowlist[start + j];
        int n1 = rowlist[start + j + 4];
        float4 v0 = *(const float4*)&x[(size_t)n0 * DIM + lane * 4];
        float4 v1 = *(const float4*)&x[(size_t)n1 * DIM + lane * 4];
        acc.x += v0.x + v1.x; acc.y += v0.y + v1.y;
        acc.z += v0.z + v1.z; acc.w += v0.w + v1.w;
    }
    if (j < cnt) {
        int n0 = rowlist[start + j];
        float4 v0 = *(const float4*)&x[(size_t)n0 * DIM + lane * 4];
        acc.x += v0.x; acc.y += v0.y; acc.z += v0.z; acc.w += v0.w;
    }
    *(float4*)&red[w][lane * 4] = acc;
    __syncthreads();
    float s = red[0][t] + red[1][t] + red[2][t] + red[3][t];
    dwT[(size_t)k * DIM + t] = s;
}

// one wave per row: quantized copy (reconstructed from planes) + loss partial
__global__ void k_gather(const float* __restrict__ x, const unsigned short* __restrict__ ehs_,
                         const int* __restrict__ idx, float* __restrict__ out_q,
                         float* __restrict__ lossp)
{
    const _Float16* ehs = (const _Float16*)ehs_;
    int t = threadIdx.x;
    int lane = t & 63, w = t >> 6;
    int n = blockIdx.x * 4 + w;
    int k = idx[n];
    float4 xv = *(const float4*)&x[(size_t)n * DIM + lane * 4];
    size_t base = (size_t)(((k >> 8) * 8) + (lane >> 3)) * 8192 + (k & 255) * 32 + (lane & 7) * 4;
    f16x4 h1 = *(const f16x4*)(ehs + base);
    f16x4 h2 = *(const f16x4*)(ehs + EH_PLANE + base);
    float4 ev;
    ev.x = (float)h1[0] + (float)h2[0];
    ev.y = (float)h1[1] + (float)h2[1];
    ev.z = (float)h1[2] + (float)h2[2];
    ev.w = (float)h1[3] + (float)h2[3];
    *(float4*)&out_q[(size_t)n * DIM + lane * 4] = ev;
    float dx = ev.x - xv.x, dy = ev.y - xv.y, dz = ev.z - xv.z, dw = ev.w - xv.w;
    float s = dx * dx + dy * dy + dz * dz + dw * dw;
#pragma unroll
    for (int off = 32; off > 0; off >>= 1) s += __shfl_down(s, off, 64);
    if (lane == 0) atomicAdd(&lossp[blockIdx.x & 255], s);
}

__global__ void k_finalize(const float* __restrict__ counts, const float* __restrict__ lossp,
                           const float* __restrict__ ema_counter,
                           const float* __restrict__ ema_cluster,
                           float* __restrict__ cnorm, float* __restrict__ scal,
                           float* __restrict__ out)
{
    __shared__ float red[256];
    int t = threadIdx.x;
    float ls = lossp[t];
    float ent = 0.0f, casum = 0.0f;
    float ca[16];
#pragma unroll
    for (int j = 0; j < 16; ++j) {
        int k = j * 256 + t;
        float c = counts[k];
        float p = c * (1.0f / 32768.0f);
        ent += p * logf(p + 1e-10f);
        ca[j] = ema_cluster[k] * 0.99f + c * 0.01f;   // cluster_hidden
        casum += ca[j];
    }
    red[t] = ls; __syncthreads();
    for (int o = 128; o > 0; o >>= 1) { if (t < o) red[t] += red[t + o]; __syncthreads(); }
    float loss_tot = red[0]; __syncthreads();
    red[t] = ent; __syncthreads();
    for (int o = 128; o > 0; o >>= 1) { if (t < o) red[t] += red[t + o]; __syncthreads(); }
    float ent_tot = red[0]; __syncthreads();
    red[t] = casum; __syncthreads();
    for (int o = 128; o > 0; o >>= 1) { if (t < o) red[t] += red[t + o]; __syncthreads(); }
    float casum_tot = red[0]; __syncthreads();

    float bias = 1.0f - powf(0.99f, ema_counter[0] + 1.0f);
    float n = casum_tot / bias;                 // sum(cluster_avg)
    float inv = n / (n + 4096.0f * 1e-5f);
#pragma unroll
    for (int j = 0; j < 16; ++j) {
        int k = j * 256 + t;
        cnorm[k] = (ca[j] / bias + 1e-5f) * inv;
    }
    if (t == 0) {
        out[OUT_LOSS] = 1.25f * loss_tot * (1.0f / (32768.0f * 256.0f));
        out[OUT_PERP] = expf(-ent_tot);
        scal[0] = bias;
    }
}

// new_embeddings[d][k] = (ema_dw*DECAY + dwT^T*(1-DECAY))/bias / cnorm[k]
__global__ void k_newemb(const float* __restrict__ dwT, const float* __restrict__ ema_dw,
                         const float* __restrict__ cnorm, const float* __restrict__ scal,
                         float* __restrict__ out_emb)
{
    __shared__ float tile[32][33];
    int t = threadIdx.x;
    int tx = t & 31, iy = t >> 5;
    int k0 = blockIdx.x * 32, d0 = blockIdx.y * 32;
#pragma unroll
    for (int j = 0; j < 4; ++j)
        tile[iy + 8 * j][tx] = dwT[(size_t)(k0 + iy + 8 * j) * DIM + d0 + tx];
    __syncthreads();
    float inv_bias = 1.0f / scal[0];
    float cn = cnorm[k0 + tx];
#pragma unroll
    for (int j = 0; j < 4; ++j) {
        int d = d0 + iy + 8 * j;
        float dwv = tile[tx][iy + 8 * j];
        float hid = ema_dw[(size_t)d * KCODE + k0 + tx] * 0.99f + dwv * 0.01f;
        out_emb[(size_t)d * KCODE + k0 + tx] = hid * inv_bias / cn;
    }
}

extern "C" void kernel_launch(void* const* d_in, const int* in_sizes, int n_in,
                              void* d_out, int out_size, void* d_ws, size_t ws_size,
                              hipStream_t stream)
{
    const float* x           = (const float*)d_in[0];
    const float* emb         = (const float*)d_in[1];
    const float* ema_counter = (const float*)d_in[2];
    const float* ema_cluster = (const float*)d_in[3];
    const float* ema_dw      = (const float*)d_in[4];
    float* out = (float*)d_out;
    float* ws  = (float*)d_ws;

    float* e2     = ws + WS_E2;
    float* counts = ws + WS_COUNTS;
    float* lossp  = ws + WS_LOSSP;
    float* scal   = ws + WS_SCAL;
    float* cnorm  = ws + WS_CNORM;
    int*   idxw   = (int*)(ws + WS_IDX);
    unsigned short* ehs = (unsigned short*)(ws + WS_EHS);
    float* dwT    = ws + WS_DWT;
    float* carryV = ws + WS_CARRYV;
    int*   carryI = (int*)(ws + WS_CARRYI);
    int*   rowlist= (int*)(ws + WS_CARRYV);   // overlays carryV (dead after argmin B)
    int*   offs   = (int*)(ws + WS_OFFS);
    int*   woff   = (int*)(ws + WS_WOFF);
    unsigned short* xh = (unsigned short*)(out + OUT_Q);  // scratch, overwritten by k_gather

    hipMemsetAsync(e2, 0, (size_t)WS_CNORM * sizeof(float), stream);  // zeros e2+counts+lossp+scal

    k_e2<<<dim3(16, 8), 256, 0, stream>>>(emb, e2);
    k_split_e<<<dim3(128, 8), 256, 0, stream>>>(emb, ehs);
    k_split_x<<<4096, 256, 0, stream>>>(x, xh);
    // two ct-half dispatches: each streams only 2 MB of ehs (fits L2 w/ headroom)
    k_argmin<<<512, 256, 0, stream>>>(xh, ehs, e2, idxw, carryV, carryI,
                                      out + OUT_IDX, counts, 0, 0);
    k_argmin<<<512, 256, 0, stream>>>(xh, ehs, e2, idxw, carryV, carryI,
                                      out + OUT_IDX, counts, 8, 1);
    // quantized output + loss (no atomic scatter-add anymore)
    k_gather<<<8192, 256, 0, stream>>>(x, ehs, idxw, out + OUT_Q, lossp);
    // counting-sort dw reduction: scan -> scatter -> per-code sum (atomic-free dwT)
    k_scan<<<1, 256, 0, stream>>>(counts, offs, woff);
    k_scatter<<<128, 256, 0, stream>>>(idxw, woff, rowlist);
    k_dw<<<4096, 256, 0, stream>>>(x, rowlist, offs, counts, dwT);
    k_finalize<<<1, 256, 0, stream>>>(counts, lossp, ema_counter, ema_cluster,
                                      cnorm, scal, out);
    k_newemb<<<dim3(128, 8), 256, 0, stream>>>(dwT, ema_dw, cnorm, scal, out + OUT_EMB);
}

// Round 7
// 363.613 us; speedup vs baseline: 1.4169x; 1.4169x over previous
//
#include <hip/hip_runtime.h>
#include <math.h>

#define N_TOK 32768
#define DIM   256
#define KCODE 4096

// ---- workspace layout (float offsets) ----
#define WS_E2      0                      // [4096]
#define WS_COUNTS  4096                   // [4096]
#define WS_LOSSP   8192                   // [256]
#define WS_SCAL    8448                   // [64]  scal[0]=bias
#define WS_CNORM   8512                   // [4096]
#define WS_IDX     12608                  // int [32768]
#define WS_EHS     307520                 // fp16 planes [2][16][8][256][32] = 4 MB
#define WS_DWT     1356096                // dwT [4096*256]
#define WS_CARRYV  2404672                // float [32768] carry best value / later rowlist
#define WS_CARRYI  2437440                // int   [32768] carry best index
#define WS_OFFS    2470208                // int [4096] bucket starts
#define WS_WOFF    2474304                // int [4096] scatter cursors

// ---- output layout (float offsets) ----
#define OUT_Q      0
#define OUT_LOSS   8388608
#define OUT_PERP   8388609
#define OUT_IDX    8388610
#define OUT_EMB    8421378

#define EH_PLANE   1048576                // halves per eh plane
#define XH_PLANE   8388608                // halves per xh plane

typedef _Float16 f16x8 __attribute__((ext_vector_type(8)));
typedef _Float16 f16x4 __attribute__((ext_vector_type(4)));
typedef float    f32x4 __attribute__((ext_vector_type(4)));

// ||e_k||^2, partials over d with atomics (e2 pre-zeroed)
__global__ void k_e2(const float* __restrict__ emb, float* __restrict__ e2)
{
    int k  = blockIdx.x * 256 + threadIdx.x;
    int d0 = blockIdx.y * 32;
    float s = 0.0f;
#pragma unroll 8
    for (int d = 0; d < 32; ++d) {
        float v = emb[(size_t)(d0 + d) * KCODE + k];
        s += v * v;
    }
    atomicAdd(&e2[k], s);
}

// x [N][D] -> split fp16 planes xh[2][N][D] (stored in d_out OUT_Q region)
__global__ void k_split_x(const float* __restrict__ x, unsigned short* __restrict__ xh)
{
    int i = (blockIdx.x * 256 + threadIdx.x) * 8;
    float4 f0 = *(const float4*)(x + i);
    float4 f1 = *(const float4*)(x + i + 4);
    float fv[8] = {f0.x, f0.y, f0.z, f0.w, f1.x, f1.y, f1.z, f1.w};
    f16x8 h1, h2;
#pragma unroll
    for (int j = 0; j < 8; ++j) {
        _Float16 a = (_Float16)fv[j];
        h1[j] = a;
        h2[j] = (_Float16)(fv[j] - (float)a);
    }
    *(f16x8*)((_Float16*)xh + i)            = h1;
    *(f16x8*)((_Float16*)xh + XH_PLANE + i) = h2;
}

// emb [D][K] -> pre-tiled split planes ehs[p][ct][ks][code&255][d&31]
__global__ void k_split_e(const float* __restrict__ emb, unsigned short* __restrict__ ehs_)
{
    __shared__ float tile[32][33];
    _Float16* ehs = (_Float16*)ehs_;
    int t  = threadIdx.x;
    int tx = t & 31, iy = t >> 5;
    int k0 = blockIdx.x * 32, d0 = blockIdx.y * 32;
#pragma unroll
    for (int j = 0; j < 4; ++j)
        tile[iy + 8 * j][tx] = emb[(size_t)(d0 + iy + 8 * j) * KCODE + k0 + tx];
    __syncthreads();
    int code = k0 + tx;
    size_t base = (size_t)(((code >> 8) * 8) + (d0 >> 5)) * 8192 + (code & 255) * 32 + iy * 4;
    f16x4 h1, h2;
#pragma unroll
    for (int j = 0; j < 4; ++j) {
        float v = tile[iy * 4 + j][tx];
        _Float16 a = (_Float16)v;
        h1[j] = a;
        h2[j] = (_Float16)(v - (float)a);
    }
    *(f16x4*)(ehs + base)            = h1;
    *(f16x4*)(ehs + EH_PLANE + base) = h2;
}

// Argmin over codes via fp16x2-split MFMA, two ct-half dispatches (2 MB L2 WS each).
// Geometry: 64-row blocks (Ah=64KB, 2 blocks/CU) — the config that measured 97 us
// with FETCH=25MB, no spills (round 3). Register liveness discipline: B fragments
// are consumed per-nf from the double-buffer (2 live B frags), NEVER all 8 hoisted
// (rounds 4/6: hoisting -> >128 live -> scratch spills, FETCH 360MB, 180-250 us).
// ONE change vs the 97us schedule: within each nf the three split-products are
// issued product-major across mf (a2b1 mf0..3, a1b2 mf0..3, a1b1 mf0..3) so the
// same accumulator is reused at distance 4 (~80cyc > MFMA latency) instead of 1.
__global__ __launch_bounds__(256, 2)
void k_argmin(const unsigned short* __restrict__ xh_, const unsigned short* __restrict__ ehs_,
              const float* __restrict__ e2, int* __restrict__ idx_out,
              float* __restrict__ carryV, int* __restrict__ carryI,
              float* __restrict__ out_idxf, float* __restrict__ counts,
              int ct0, int phase)
{
    __shared__ __align__(16) _Float16 Ah[2][64][256];   // 64 KB; XOR-swizzled 8-elem groups

    const _Float16* xh  = (const _Float16*)xh_;
    const _Float16* ehs = (const _Float16*)ehs_;

    const int t    = threadIdx.x;
    const int lane = t & 63, w = t >> 6;
    const int lo   = lane & 15, q = lane >> 4;
    const int row0 = blockIdx.x * 64;

    // ---- prologue: stage A planes from xh (rows m and m+32), non-temporal ----
    {
        int m = t >> 3, kb = (t & 7) * 32;
#pragma unroll
        for (int p = 0; p < 2; ++p)
#pragma unroll
            for (int rr = 0; rr < 2; ++rr) {
                int mm = m + 32 * rr;
                const _Float16* src = xh + (size_t)p * XH_PLANE + (size_t)(row0 + mm) * DIM + kb;
#pragma unroll
                for (int g = 0; g < 4; ++g) {
                    f16x8 h = __builtin_nontemporal_load((const f16x8*)(src + g * 8));
                    int grp = ((kb >> 3) + g) ^ (mm & 7);
                    *(f16x8*)&Ah[p][mm][grp * 8] = h;
                }
            }
    }
    __syncthreads();   // the ONLY barrier before the epilogue

    float best[16];
    int   bidx[16];
#pragma unroll
    for (int s = 0; s < 16; ++s) { best[s] = 3.4e38f; bidx[s] = 0; }

    // B fragment base: code-within-tile crow = w*64 + nf*16 + lo, d-off q*8
    const _Float16* ehp1 = ehs + (size_t)(w * 64 + lo) * 32 + q * 8;
    const _Float16* ehp2 = ehp1 + EH_PLANE;

    // register double-buffer for B fragments; parity = ks&1 (ks fully unrolled)
    f16x8 b1f[2][4], b2f[2][4];

    // prime: load B for so = ct0*8
    {
        const size_t so0 = (size_t)(ct0 * 8) * 8192;
#pragma unroll
        for (int nf = 0; nf < 4; ++nf) {
            b1f[0][nf] = *(const f16x8*)(ehp1 + so0 + nf * 512);
            b2f[0][nf] = *(const f16x8*)(ehp2 + so0 + nf * 512);
        }
    }

    for (int ct = ct0; ct < ct0 + 8; ++ct) {
        f32x4 acc[4][4];
#pragma unroll
        for (int mf = 0; mf < 4; ++mf)
#pragma unroll
            for (int nf = 0; nf < 4; ++nf) acc[mf][nf] = (f32x4)0.0f;

#pragma unroll
        for (int ks = 0; ks < 8; ++ks) {
            const int cur = ks & 1, nxt = cur ^ 1;
            const int so  = ct * 8 + ks;

            // ---- prefetch B for so+1 into the other parity buffer ----
            if (ks < 7 || ct < ct0 + 7) {
                const size_t po = (size_t)(so + 1) * 8192;
#pragma unroll
                for (int nf = 0; nf < 4; ++nf) {
                    b1f[nxt][nf] = *(const f16x8*)(ehp1 + po + nf * 512);
                    b2f[nxt][nf] = *(const f16x8*)(ehp2 + po + nf * 512);
                }
            }
            // pin the prefetch ahead of the MFMA cluster
            __builtin_amdgcn_sched_barrier(0);

            // ---- A fragments via LDS (conflict-free b128 via XOR swizzle) ----
            const int agrp = ((ks * 4 + q) ^ (lo & 7)) * 8;
            f16x8 a1[4], a2[4];
#pragma unroll
            for (int mf = 0; mf < 4; ++mf)
                a2[mf] = *(const f16x8*)&Ah[1][mf * 16 + lo][agrp];
#pragma unroll
            for (int mf = 0; mf < 4; ++mf)
                a1[mf] = *(const f16x8*)&Ah[0][mf * 16 + lo][agrp];

            // ---- MFMA cluster: per nf, product-major across mf (reuse dist 4) ----
            __builtin_amdgcn_s_setprio(1);
#pragma unroll
            for (int nf = 0; nf < 4; ++nf) {
#pragma unroll
                for (int mf = 0; mf < 4; ++mf)
                    acc[mf][nf] = __builtin_amdgcn_mfma_f32_16x16x32_f16(a2[mf], b1f[cur][nf], acc[mf][nf], 0, 0, 0);
#pragma unroll
                for (int mf = 0; mf < 4; ++mf)
                    acc[mf][nf] = __builtin_amdgcn_mfma_f32_16x16x32_f16(a1[mf], b2f[cur][nf], acc[mf][nf], 0, 0, 0);
#pragma unroll
                for (int mf = 0; mf < 4; ++mf)
                    acc[mf][nf] = __builtin_amdgcn_mfma_f32_16x16x32_f16(a1[mf], b1f[cur][nf], acc[mf][nf], 0, 0, 0);
            }
            __builtin_amdgcn_s_setprio(0);
        }

        // fold: dist = e2 - 2*score (x^2 row-constant dropped). codes ascending in ct,nf.
#pragma unroll
        for (int nf = 0; nf < 4; ++nf) {
            int cl = w * 64 + nf * 16 + lo;
            float e2v = e2[ct * 256 + cl];
#pragma unroll
            for (int mf = 0; mf < 4; ++mf)
#pragma unroll
                for (int r = 0; r < 4; ++r) {
                    float dist = fmaf(-2.0f, acc[mf][nf][r], e2v);
                    int s = mf * 4 + r;
                    if (dist < best[s]) { best[s] = dist; bidx[s] = ct * 256 + cl; }
                }
        }
    }

    // ---- final argmin reduction (scratch overlays Ah) ----
    __syncthreads();
    float* rv = (float*)&Ah[0][0][0];                 // [64 rows][64 slots]
    int*   ri = (int*)(((char*)&Ah[0][0][0]) + 16384);
#pragma unroll
    for (int s = 0; s < 16; ++s) {
        int row = (s >> 2) * 16 + q * 4 + (s & 3);    // mf*16 + q*4 + r
        rv[row * 64 + w * 16 + lo] = best[s];
        ri[row * 64 + w * 16 + lo] = bidx[s];
    }
    __syncthreads();
    if (t < 64) {
        float bv; int bi;
        if (phase) { bv = carryV[row0 + t]; bi = carryI[row0 + t]; }
        else       { bv = 3.4e38f; bi = 0x40000000; }
        // staggered scan start -> conflict-free
        for (int jj = 0; jj < 64; ++jj) {
            int j = (jj + t) & 63;
            float v = rv[t * 64 + j];
            int  ii = ri[t * 64 + j];
            if (v < bv || (v == bv && ii < bi)) { bv = v; bi = ii; }
        }
        if (phase) {
            idx_out[row0 + t] = bi;
            out_idxf[row0 + t] = (float)bi;
            atomicAdd(&counts[bi], 1.0f);
        } else {
            carryV[row0 + t] = bv; carryI[row0 + t] = bi;
        }
    }
}

// exclusive prefix sum over counts[4096] -> offs, woff (one block, 256 threads x 16)
__global__ void k_scan(const float* __restrict__ counts, int* __restrict__ offs,
                       int* __restrict__ woff)
{
    __shared__ int ps[256];
    int t = threadIdx.x;
    int local[16];
    int s = 0;
#pragma unroll
    for (int j = 0; j < 16; ++j) {
        local[j] = s;
        s += (int)counts[t * 16 + j];
    }
    ps[t] = s;
    __syncthreads();
    for (int off = 1; off < 256; off <<= 1) {
        int v = (t >= off) ? ps[t - off] : 0;
        __syncthreads();
        ps[t] += v;
        __syncthreads();
    }
    int base = (t > 0) ? ps[t - 1] : 0;
#pragma unroll
    for (int j = 0; j < 16; ++j) {
        int o = base + local[j];
        offs[t * 16 + j] = o;
        woff[t * 16 + j] = o;
    }
}

// rowlist[pos] = n, grouped by code (counting-sort scatter)
__global__ void k_scatter(const int* __restrict__ idx, int* __restrict__ woff,
                          int* __restrict__ rowlist)
{
    int n = blockIdx.x * 256 + threadIdx.x;
    int k = idx[n];
    int pos = atomicAdd(&woff[k], 1);
    rowlist[pos] = n;
}

// dwT[k][d] = sum of x rows assigned to code k — one block per code, NO atomics
__global__ void k_dw(const float* __restrict__ x, const int* __restrict__ rowlist,
                     const int* __restrict__ offs, const float* __restrict__ counts,
                     float* __restrict__ dwT)
{
    __shared__ float red[4][256];
    int k = blockIdx.x;
    int t = threadIdx.x;
    int lane = t & 63, w = t >> 6;
    int start = offs[k];
    int cnt   = (int)counts[k];
    float4 acc = {0.0f, 0.0f, 0.0f, 0.0f};
    int j = w;
    for (; j + 4 < cnt; j += 8) {
        int n0 = rowlist[start + j];
        int n1 = rowlist[start + j + 4];
        float4 v0 = *(const float4*)&x[(size_t)n0 * DIM + lane * 4];
        float4 v1 = *(const float4*)&x[(size_t)n1 * DIM + lane * 4];
        acc.x += v0.x + v1.x; acc.y += v0.y + v1.y;
        acc.z += v0.z + v1.z; acc.w += v0.w + v1.w;
    }
    if (j < cnt) {
        int n0 = rowlist[start + j];
        float4 v0 = *(const float4*)&x[(size_t)n0 * DIM + lane * 4];
        acc.x += v0.x; acc.y += v0.y; acc.z += v0.z; acc.w += v0.w;
    }
    *(float4*)&red[w][lane * 4] = acc;
    __syncthreads();
    float s = red[0][t] + red[1][t] + red[2][t] + red[3][t];
    dwT[(size_t)k * DIM + t] = s;
}

// one wave per row: quantized copy (reconstructed from planes) + loss partial
__global__ void k_gather(const float* __restrict__ x, const unsigned short* __restrict__ ehs_,
                         const int* __restrict__ idx, float* __restrict__ out_q,
                         float* __restrict__ lossp)
{
    const _Float16* ehs = (const _Float16*)ehs_;
    int t = threadIdx.x;
    int lane = t & 63, w = t >> 6;
    int n = blockIdx.x * 4 + w;
    int k = idx[n];
    float4 xv = *(const float4*)&x[(size_t)n * DIM + lane * 4];
    size_t base = (size_t)(((k >> 8) * 8) + (lane >> 3)) * 8192 + (k & 255) * 32 + (lane & 7) * 4;
    f16x4 h1 = *(const f16x4*)(ehs + base);
    f16x4 h2 = *(const f16x4*)(ehs + EH_PLANE + base);
    float4 ev;
    ev.x = (float)h1[0] + (float)h2[0];
    ev.y = (float)h1[1] + (float)h2[1];
    ev.z = (float)h1[2] + (float)h2[2];
    ev.w = (float)h1[3] + (float)h2[3];
    *(float4*)&out_q[(size_t)n * DIM + lane * 4] = ev;
    float dx = ev.x - xv.x, dy = ev.y - xv.y, dz = ev.z - xv.z, dw = ev.w - xv.w;
    float s = dx * dx + dy * dy + dz * dz + dw * dw;
#pragma unroll
    for (int off = 32; off > 0; off >>= 1) s += __shfl_down(s, off, 64);
    if (lane == 0) atomicAdd(&lossp[blockIdx.x & 255], s);
}

__global__ void k_finalize(const float* __restrict__ counts, const float* __restrict__ lossp,
                           const float* __restrict__ ema_counter,
                           const float* __restrict__ ema_cluster,
                           float* __restrict__ cnorm, float* __restrict__ scal,
                           float* __restrict__ out)
{
    __shared__ float red[256];
    int t = threadIdx.x;
    float ls = lossp[t];
    float ent = 0.0f, casum = 0.0f;
    float ca[16];
#pragma unroll
    for (int j = 0; j < 16; ++j) {
        int k = j * 256 + t;
        float c = counts[k];
        float p = c * (1.0f / 32768.0f);
        ent += p * logf(p + 1e-10f);
        ca[j] = ema_cluster[k] * 0.99f + c * 0.01f;   // cluster_hidden
        casum += ca[j];
    }
    red[t] = ls; __syncthreads();
    for (int o = 128; o > 0; o >>= 1) { if (t < o) red[t] += red[t + o]; __syncthreads(); }
    float loss_tot = red[0]; __syncthreads();
    red[t] = ent; __syncthreads();
    for (int o = 128; o > 0; o >>= 1) { if (t < o) red[t] += red[t + o]; __syncthreads(); }
    float ent_tot = red[0]; __syncthreads();
    red[t] = casum; __syncthreads();
    for (int o = 128; o > 0; o >>= 1) { if (t < o) red[t] += red[t + o]; __syncthreads(); }
    float casum_tot = red[0]; __syncthreads();

    float bias = 1.0f - powf(0.99f, ema_counter[0] + 1.0f);
    float n = casum_tot / bias;                 // sum(cluster_avg)
    float inv = n / (n + 4096.0f * 1e-5f);
#pragma unroll
    for (int j = 0; j < 16; ++j) {
        int k = j * 256 + t;
        cnorm[k] = (ca[j] / bias + 1e-5f) * inv;
    }
    if (t == 0) {
        out[OUT_LOSS] = 1.25f * loss_tot * (1.0f / (32768.0f * 256.0f));
        out[OUT_PERP] = expf(-ent_tot);
        scal[0] = bias;
    }
}

// new_embeddings[d][k] = (ema_dw*DECAY + dwT^T*(1-DECAY))/bias / cnorm[k]
__global__ void k_newemb(const float* __restrict__ dwT, const float* __restrict__ ema_dw,
                         const float* __restrict__ cnorm, const float* __restrict__ scal,
                         float* __restrict__ out_emb)
{
    __shared__ float tile[32][33];
    int t = threadIdx.x;
    int tx = t & 31, iy = t >> 5;
    int k0 = blockIdx.x * 32, d0 = blockIdx.y * 32;
#pragma unroll
    for (int j = 0; j < 4; ++j)
        tile[iy + 8 * j][tx] = dwT[(size_t)(k0 + iy + 8 * j) * DIM + d0 + tx];
    __syncthreads();
    float inv_bias = 1.0f / scal[0];
    float cn = cnorm[k0 + tx];
#pragma unroll
    for (int j = 0; j < 4; ++j) {
        int d = d0 + iy + 8 * j;
        float dwv = tile[tx][iy + 8 * j];
        float hid = ema_dw[(size_t)d * KCODE + k0 + tx] * 0.99f + dwv * 0.01f;
        out_emb[(size_t)d * KCODE + k0 + tx] = hid * inv_bias / cn;
    }
}

extern "C" void kernel_launch(void* const* d_in, const int* in_sizes, int n_in,
                              void* d_out, int out_size, void* d_ws, size_t ws_size,
                              hipStream_t stream)
{
    const float* x           = (const float*)d_in[0];
    const float* emb         = (const float*)d_in[1];
    const float* ema_counter = (const float*)d_in[2];
    const float* ema_cluster = (const float*)d_in[3];
    const float* ema_dw      = (const float*)d_in[4];
    float* out = (float*)d_out;
    float* ws  = (float*)d_ws;

    float* e2     = ws + WS_E2;
    float* counts = ws + WS_COUNTS;
    float* lossp  = ws + WS_LOSSP;
    float* scal   = ws + WS_SCAL;
    float* cnorm  = ws + WS_CNORM;
    int*   idxw   = (int*)(ws + WS_IDX);
    unsigned short* ehs = (unsigned short*)(ws + WS_EHS);
    float* dwT    = ws + WS_DWT;
    float* carryV = ws + WS_CARRYV;
    int*   carryI = (int*)(ws + WS_CARRYI);
    int*   rowlist= (int*)(ws + WS_CARRYV);   // overlays carryV (dead after argmin B)
    int*   offs   = (int*)(ws + WS_OFFS);
    int*   woff   = (int*)(ws + WS_WOFF);
    unsigned short* xh = (unsigned short*)(out + OUT_Q);  // scratch, overwritten by k_gather

    hipMemsetAsync(e2, 0, (size_t)WS_CNORM * sizeof(float), stream);  // zeros e2+counts+lossp+scal

    k_e2<<<dim3(16, 8), 256, 0, stream>>>(emb, e2);
    k_split_e<<<dim3(128, 8), 256, 0, stream>>>(emb, ehs);
    k_split_x<<<4096, 256, 0, stream>>>(x, xh);
    // two ct-half dispatches: each streams only 2 MB of ehs (fits L2 w/ headroom)
    k_argmin<<<512, 256, 0, stream>>>(xh, ehs, e2, idxw, carryV, carryI,
                                      out + OUT_IDX, counts, 0, 0);
    k_argmin<<<512, 256, 0, stream>>>(xh, ehs, e2, idxw, carryV, carryI,
                                      out + OUT_IDX, counts, 8, 1);
    // quantized output + loss (no atomic scatter-add anymore)
    k_gather<<<8192, 256, 0, stream>>>(x, ehs, idxw, out + OUT_Q, lossp);
    // counting-sort dw reduction: scan -> scatter -> per-code sum (atomic-free dwT)
    k_scan<<<1, 256, 0, stream>>>(counts, offs, woff);
    k_scatter<<<128, 256, 0, stream>>>(idxw, woff, rowlist);
    k_dw<<<4096, 256, 0, stream>>>(x, rowlist, offs, counts, dwT);
    k_finalize<<<1, 256, 0, stream>>>(counts, lossp, ema_counter, ema_cluster,
                                      cnorm, scal, out);
    k_newemb<<<dim3(128, 8), 256, 0, stream>>>(dwT, ema_dw, cnorm, scal, out + OUT_EMB);
}

// Round 9
// 326.257 us; speedup vs baseline: 1.5792x; 1.1145x over previous
//
#include <hip/hip_runtime.h>
#include <math.h>

#define N_TOK 32768
#define DIM   256
#define KCODE 4096

// ---- workspace layout (float offsets) ----
#define WS_E2      0                      // [4096]
#define WS_COUNTS  4096                   // [4096]
#define WS_LOSSP   8192                   // [256]
#define WS_SCAL    8448                   // [64]  scal[0]=bias
#define WS_CNORM   8512                   // [4096]
#define WS_IDX     12608                  // int [32768]
#define WS_EHS     307520                 // fp16 planes [2][16][8][256][32] = 4 MB
#define WS_DWT     1356096                // dwT [4096*256]
#define WS_CARRYV  2404672                // float [32768] carry best value / later rowlist
#define WS_CARRYI  2437440                // int   [32768] carry best index
#define WS_OFFS    2470208                // int [4096] bucket starts
#define WS_WOFF    2474304                // int [4096] scatter cursors

// ---- output layout (float offsets) ----
#define OUT_Q      0
#define OUT_LOSS   8388608
#define OUT_PERP   8388609
#define OUT_IDX    8388610
#define OUT_EMB    8421378

#define EH_PLANE   1048576                // halves per eh plane

typedef _Float16 f16x8 __attribute__((ext_vector_type(8)));
typedef _Float16 f16x4 __attribute__((ext_vector_type(4)));
typedef float    f32x4 __attribute__((ext_vector_type(4)));

// emb [D][K] -> pre-tiled split planes ehs[p][ct][ks][code&255][d&31]
// ALSO accumulates e2[k] = sum_d emb[d][k]^2 (absorbs the old k_e2 kernel;
// e2 is memset-zeroed before this runs).
__global__ void k_split_e(const float* __restrict__ emb, unsigned short* __restrict__ ehs_,
                          float* __restrict__ e2)
{
    __shared__ float tile[32][33];
    _Float16* ehs = (_Float16*)ehs_;
    int t  = threadIdx.x;
    int tx = t & 31, iy = t >> 5;
    int k0 = blockIdx.x * 32, d0 = blockIdx.y * 32;
#pragma unroll
    for (int j = 0; j < 4; ++j)
        tile[iy + 8 * j][tx] = emb[(size_t)(d0 + iy + 8 * j) * KCODE + k0 + tx];
    __syncthreads();
    int code = k0 + tx;
    size_t base = (size_t)(((code >> 8) * 8) + (d0 >> 5)) * 8192 + (code & 255) * 32 + iy * 4;
    f16x4 h1, h2;
    float ssq = 0.0f;
#pragma unroll
    for (int j = 0; j < 4; ++j) {
        float v = tile[iy * 4 + j][tx];
        ssq += v * v;
        _Float16 a = (_Float16)v;
        h1[j] = a;
        h2[j] = (_Float16)(v - (float)a);
    }
    *(f16x4*)(ehs + base)            = h1;
    *(f16x4*)(ehs + EH_PLANE + base) = h2;
    atomicAdd(&e2[code], ssq);   // 64 adds per code total — trivial contention
}

// Argmin over codes via fp16x2-split MFMA, two ct-half dispatches (2 MB L2 WS each).
// MFMA core is the verified 101us/45% schedule (rounds 3/7) — UNTOUCHED.
// Prologue reads x (f32) DIRECTLY and does the fp16 split during staging
// (identical global bytes: 2 f16 planes == 1 f32 plane), which deletes the
// separate k_split_x pass (64 MB of traffic + a launch).
__global__ __launch_bounds__(256, 2)
void k_argmin(const float* __restrict__ x, const unsigned short* __restrict__ ehs_,
              const float* __restrict__ e2, int* __restrict__ idx_out,
              float* __restrict__ carryV, int* __restrict__ carryI,
              float* __restrict__ out_idxf, float* __restrict__ counts,
              int ct0, int phase)
{
    __shared__ __align__(16) _Float16 Ah[2][64][256];   // 64 KB; XOR-swizzled 8-elem groups

    const _Float16* ehs = (const _Float16*)ehs_;

    const int t    = threadIdx.x;
    const int lane = t & 63, w = t >> 6;
    const int lo   = lane & 15, q = lane >> 4;
    const int row0 = blockIdx.x * 64;

    // ---- prologue: stage A planes from x with on-the-fly fp16 split ----
    {
        int m = t >> 3, kb = (t & 7) * 32;
#pragma unroll
        for (int rr = 0; rr < 2; ++rr) {
            int mm = m + 32 * rr;
            const float* src = x + (size_t)(row0 + mm) * DIM + kb;
#pragma unroll
            for (int g = 0; g < 4; ++g) {
                f32x4 f0 = __builtin_nontemporal_load((const f32x4*)(src + g * 8));
                f32x4 f1 = __builtin_nontemporal_load((const f32x4*)(src + g * 8 + 4));
                f16x8 h1, h2;
#pragma unroll
                for (int j = 0; j < 4; ++j) {
                    _Float16 a = (_Float16)f0[j];
                    h1[j] = a; h2[j] = (_Float16)(f0[j] - (float)a);
                    _Float16 b = (_Float16)f1[j];
                    h1[j + 4] = b; h2[j + 4] = (_Float16)(f1[j] - (float)b);
                }
                int grp = ((kb >> 3) + g) ^ (mm & 7);
                *(f16x8*)&Ah[0][mm][grp * 8] = h1;
                *(f16x8*)&Ah[1][mm][grp * 8] = h2;
            }
        }
    }
    __syncthreads();   // the ONLY barrier before the epilogue

    float best[16];
    int   bidx[16];
#pragma unroll
    for (int s = 0; s < 16; ++s) { best[s] = 3.4e38f; bidx[s] = 0; }

    // B fragment base: code-within-tile crow = w*64 + nf*16 + lo, d-off q*8
    const _Float16* ehp1 = ehs + (size_t)(w * 64 + lo) * 32 + q * 8;
    const _Float16* ehp2 = ehp1 + EH_PLANE;

    // register double-buffer for B fragments; parity = ks&1 (ks fully unrolled)
    f16x8 b1f[2][4], b2f[2][4];

    // prime: load B for so = ct0*8
    {
        const size_t so0 = (size_t)(ct0 * 8) * 8192;
#pragma unroll
        for (int nf = 0; nf < 4; ++nf) {
            b1f[0][nf] = *(const f16x8*)(ehp1 + so0 + nf * 512);
            b2f[0][nf] = *(const f16x8*)(ehp2 + so0 + nf * 512);
        }
    }

    for (int ct = ct0; ct < ct0 + 8; ++ct) {
        f32x4 acc[4][4];
#pragma unroll
        for (int mf = 0; mf < 4; ++mf)
#pragma unroll
            for (int nf = 0; nf < 4; ++nf) acc[mf][nf] = (f32x4)0.0f;

#pragma unroll
        for (int ks = 0; ks < 8; ++ks) {
            const int cur = ks & 1, nxt = cur ^ 1;
            const int so  = ct * 8 + ks;

            // ---- prefetch B for so+1 into the other parity buffer ----
            if (ks < 7 || ct < ct0 + 7) {
                const size_t po = (size_t)(so + 1) * 8192;
#pragma unroll
                for (int nf = 0; nf < 4; ++nf) {
                    b1f[nxt][nf] = *(const f16x8*)(ehp1 + po + nf * 512);
                    b2f[nxt][nf] = *(const f16x8*)(ehp2 + po + nf * 512);
                }
            }
            // pin the prefetch ahead of the MFMA cluster
            __builtin_amdgcn_sched_barrier(0);

            // ---- A fragments via LDS (conflict-free b128 via XOR swizzle) ----
            const int agrp = ((ks * 4 + q) ^ (lo & 7)) * 8;
            f16x8 a1[4], a2[4];
#pragma unroll
            for (int mf = 0; mf < 4; ++mf)
                a2[mf] = *(const f16x8*)&Ah[1][mf * 16 + lo][agrp];
#pragma unroll
            for (int mf = 0; mf < 4; ++mf)
                a1[mf] = *(const f16x8*)&Ah[0][mf * 16 + lo][agrp];

            // ---- MFMA cluster: per nf, product-major across mf (reuse dist 4) ----
            __builtin_amdgcn_s_setprio(1);
#pragma unroll
            for (int nf = 0; nf < 4; ++nf) {
#pragma unroll
                for (int mf = 0; mf < 4; ++mf)
                    acc[mf][nf] = __builtin_amdgcn_mfma_f32_16x16x32_f16(a2[mf], b1f[cur][nf], acc[mf][nf], 0, 0, 0);
#pragma unroll
                for (int mf = 0; mf < 4; ++mf)
                    acc[mf][nf] = __builtin_amdgcn_mfma_f32_16x16x32_f16(a1[mf], b2f[cur][nf], acc[mf][nf], 0, 0, 0);
#pragma unroll
                for (int mf = 0; mf < 4; ++mf)
                    acc[mf][nf] = __builtin_amdgcn_mfma_f32_16x16x32_f16(a1[mf], b1f[cur][nf], acc[mf][nf], 0, 0, 0);
            }
            __builtin_amdgcn_s_setprio(0);
        }

        // fold: dist = e2 - 2*score (x^2 row-constant dropped). codes ascending in ct,nf.
#pragma unroll
        for (int nf = 0; nf < 4; ++nf) {
            int cl = w * 64 + nf * 16 + lo;
            float e2v = e2[ct * 256 + cl];
#pragma unroll
            for (int mf = 0; mf < 4; ++mf)
#pragma unroll
                for (int r = 0; r < 4; ++r) {
                    float dist = fmaf(-2.0f, acc[mf][nf][r], e2v);
                    int s = mf * 4 + r;
                    if (dist < best[s]) { best[s] = dist; bidx[s] = ct * 256 + cl; }
                }
        }
    }

    // ---- final argmin reduction (scratch overlays Ah) ----
    __syncthreads();
    float* rv = (float*)&Ah[0][0][0];                 // [64 rows][64 slots]
    int*   ri = (int*)(((char*)&Ah[0][0][0]) + 16384);
#pragma unroll
    for (int s = 0; s < 16; ++s) {
        int row = (s >> 2) * 16 + q * 4 + (s & 3);    // mf*16 + q*4 + r
        rv[row * 64 + w * 16 + lo] = best[s];
        ri[row * 64 + w * 16 + lo] = bidx[s];
    }
    __syncthreads();
    if (t < 64) {
        float bv; int bi;
        if (phase) { bv = carryV[row0 + t]; bi = carryI[row0 + t]; }
        else       { bv = 3.4e38f; bi = 0x40000000; }
        // staggered scan start -> conflict-free
        for (int jj = 0; jj < 64; ++jj) {
            int j = (jj + t) & 63;
            float v = rv[t * 64 + j];
            int  ii = ri[t * 64 + j];
            if (v < bv || (v == bv && ii < bi)) { bv = v; bi = ii; }
        }
        if (phase) {
            idx_out[row0 + t] = bi;
            out_idxf[row0 + t] = (float)bi;
            atomicAdd(&counts[bi], 1.0f);
        } else {
            carryV[row0 + t] = bv; carryI[row0 + t] = bi;
        }
    }
}

// exclusive prefix sum over counts[4096] -> offs, woff (one block, 256 threads x 16)
__global__ void k_scan(const float* __restrict__ counts, int* __restrict__ offs,
                       int* __restrict__ woff)
{
    __shared__ int ps[256];
    int t = threadIdx.x;
    int local[16];
    int s = 0;
#pragma unroll
    for (int j = 0; j < 16; ++j) {
        local[j] = s;
        s += (int)counts[t * 16 + j];
    }
    ps[t] = s;
    __syncthreads();
    for (int off = 1; off < 256; off <<= 1) {
        int v = (t >= off) ? ps[t - off] : 0;
        __syncthreads();
        ps[t] += v;
        __syncthreads();
    }
    int base = (t > 0) ? ps[t - 1] : 0;
#pragma unroll
    for (int j = 0; j < 16; ++j) {
        int o = base + local[j];
        offs[t * 16 + j] = o;
        woff[t * 16 + j] = o;
    }
}

// rowlist[pos] = n, grouped by code (counting-sort scatter)
__global__ void k_scatter(const int* __restrict__ idx, int* __restrict__ woff,
                          int* __restrict__ rowlist)
{
    int n = blockIdx.x * 256 + threadIdx.x;
    int k = idx[n];
    int pos = atomicAdd(&woff[k], 1);
    rowlist[pos] = n;
}

// Per-code fused update: one block per code k.
//   dwT[k][:]  = sum of x rows in bucket k          (atomic-free)
//   out_q[n,:] = e_k  for every row n in bucket     (absorbs old k_gather)
//   lossp     += cnt*|e|^2 - 2*e.dw + sum|x|^2      (algebraic bucket loss)
__global__ void k_dw(const float* __restrict__ x, const unsigned short* __restrict__ ehs_,
                     const int* __restrict__ rowlist, const int* __restrict__ offs,
                     const float* __restrict__ counts, float* __restrict__ dwT,
                     float* __restrict__ out_q, float* __restrict__ lossp)
{
    __shared__ __align__(16) float es[256];
    __shared__ __align__(16) float red[4][256];
    const _Float16* ehs = (const _Float16*)ehs_;
    int k = blockIdx.x, t = threadIdx.x;
    int lane = t & 63, w = t >> 6;
    // reconstruct e_k: thread t -> dimension d = t
    size_t base = (size_t)(((k >> 8) * 8) + (t >> 5)) * 8192 + (k & 255) * 32 + (t & 31);
    float e = (float)ehs[base] + (float)ehs[EH_PLANE + base];
    es[t] = e;
    int start = offs[k];
    int cnt   = (int)counts[k];
    __syncthreads();
    float4 ev = *(const float4*)&es[lane * 4];
    float4 acc = {0.0f, 0.0f, 0.0f, 0.0f};
    float sq = 0.0f;
    for (int j = w; j < cnt; j += 4) {
        int n = rowlist[start + j];
        float4 xv = *(const float4*)&x[(size_t)n * DIM + lane * 4];
        acc.x += xv.x; acc.y += xv.y; acc.z += xv.z; acc.w += xv.w;
        sq += xv.x * xv.x + xv.y * xv.y + xv.z * xv.z + xv.w * xv.w;
        *(float4*)&out_q[(size_t)n * DIM + lane * 4] = ev;
    }
    *(float4*)&red[w][lane * 4] = acc;
    __syncthreads();
    float s = red[0][t] + red[1][t] + red[2][t] + red[3][t];
    dwT[(size_t)k * DIM + t] = s;
    // bucket loss reduction: dot(e,dw), |e|^2, sum|x|^2
    float v1 = es[t] * s;     // dot partial (each t = unique d)
    float v2 = e * e;         // |e|^2 partial
    float v3 = sq;            // sum x^2 partial
#pragma unroll
    for (int off = 32; off > 0; off >>= 1) {
        v1 += __shfl_down(v1, off, 64);
        v2 += __shfl_down(v2, off, 64);
        v3 += __shfl_down(v3, off, 64);
    }
    __syncthreads();
    if (lane == 0) { red[0][w] = v1; red[1][w] = v2; red[2][w] = v3; }
    __syncthreads();
    if (t == 0 && cnt > 0) {
        float dot = red[0][0] + red[0][1] + red[0][2] + red[0][3];
        float e2t = red[1][0] + red[1][1] + red[1][2] + red[1][3];
        float sqt = red[2][0] + red[2][1] + red[2][2] + red[2][3];
        atomicAdd(&lossp[k & 255], (float)cnt * e2t - 2.0f * dot + sqt);
    }
}

__global__ void k_finalize(const float* __restrict__ counts, const float* __restrict__ lossp,
                           const float* __restrict__ ema_counter,
                           const float* __restrict__ ema_cluster,
                           float* __restrict__ cnorm, float* __restrict__ scal,
                           float* __restrict__ out)
{
    __shared__ float red[256];
    int t = threadIdx.x;
    float ls = lossp[t];
    float ent = 0.0f, casum = 0.0f;
    float ca[16];
#pragma unroll
    for (int j = 0; j < 16; ++j) {
        int k = j * 256 + t;
        float c = counts[k];
        float p = c * (1.0f / 32768.0f);
        ent += p * logf(p + 1e-10f);
        ca[j] = ema_cluster[k] * 0.99f + c * 0.01f;   // cluster_hidden
        casum += ca[j];
    }
    red[t] = ls; __syncthreads();
    for (int o = 128; o > 0; o >>= 1) { if (t < o) red[t] += red[t + o]; __syncthreads(); }
    float loss_tot = red[0]; __syncthreads();
    red[t] = ent; __syncthreads();
    for (int o = 128; o > 0; o >>= 1) { if (t < o) red[t] += red[t + o]; __syncthreads(); }
    float ent_tot = red[0]; __syncthreads();
    red[t] = casum; __syncthreads();
    for (int o = 128; o > 0; o >>= 1) { if (t < o) red[t] += red[t + o]; __syncthreads(); }
    float casum_tot = red[0]; __syncthreads();

    float bias = 1.0f - powf(0.99f, ema_counter[0] + 1.0f);
    float n = casum_tot / bias;                 // sum(cluster_avg)
    float inv = n / (n + 4096.0f * 1e-5f);
#pragma unroll
    for (int j = 0; j < 16; ++j) {
        int k = j * 256 + t;
        cnorm[k] = (ca[j] / bias + 1e-5f) * inv;
    }
    if (t == 0) {
        out[OUT_LOSS] = 1.25f * loss_tot * (1.0f / (32768.0f * 256.0f));
        out[OUT_PERP] = expf(-ent_tot);
        scal[0] = bias;
    }
}

// new_embeddings[d][k] = (ema_dw*DECAY + dwT^T*(1-DECAY))/bias / cnorm[k]
__global__ void k_newemb(const float* __restrict__ dwT, const float* __restrict__ ema_dw,
                         const float* __restrict__ cnorm, const float* __restrict__ scal,
                         float* __restrict__ out_emb)
{
    __shared__ float tile[32][33];
    int t = threadIdx.x;
    int tx = t & 31, iy = t >> 5;
    int k0 = blockIdx.x * 32, d0 = blockIdx.y * 32;
#pragma unroll
    for (int j = 0; j < 4; ++j)
        tile[iy + 8 * j][tx] = dwT[(size_t)(k0 + iy + 8 * j) * DIM + d0 + tx];
    __syncthreads();
    float inv_bias = 1.0f / scal[0];
    float cn = cnorm[k0 + tx];
#pragma unroll
    for (int j = 0; j < 4; ++j) {
        int d = d0 + iy + 8 * j;
        float dwv = tile[tx][iy + 8 * j];
        float hid = ema_dw[(size_t)d * KCODE + k0 + tx] * 0.99f + dwv * 0.01f;
        out_emb[(size_t)d * KCODE + k0 + tx] = hid * inv_bias / cn;
    }
}

extern "C" void kernel_launch(void* const* d_in, const int* in_sizes, int n_in,
                              void* d_out, int out_size, void* d_ws, size_t ws_size,
                              hipStream_t stream)
{
    const float* x           = (const float*)d_in[0];
    const float* emb         = (const float*)d_in[1];
    const float* ema_counter = (const float*)d_in[2];
    const float* ema_cluster = (const float*)d_in[3];
    const float* ema_dw      = (const float*)d_in[4];
    float* out = (float*)d_out;
    float* ws  = (float*)d_ws;

    float* e2     = ws + WS_E2;
    float* counts = ws + WS_COUNTS;
    float* lossp  = ws + WS_LOSSP;
    float* scal   = ws + WS_SCAL;
    float* cnorm  = ws + WS_CNORM;
    int*   idxw   = (int*)(ws + WS_IDX);
    unsigned short* ehs = (unsigned short*)(ws + WS_EHS);
    float* dwT    = ws + WS_DWT;
    float* carryV = ws + WS_CARRYV;
    int*   carryI = (int*)(ws + WS_CARRYI);
    int*   rowlist= (int*)(ws + WS_CARRYV);   // overlays carryV (dead after argmin B)
    int*   offs   = (int*)(ws + WS_OFFS);
    int*   woff   = (int*)(ws + WS_WOFF);

    hipMemsetAsync(e2, 0, (size_t)WS_CNORM * sizeof(float), stream);  // zeros e2+counts+lossp+scal

    // emb -> split planes + e2 (k_e2 absorbed)
    k_split_e<<<dim3(128, 8), 256, 0, stream>>>(emb, ehs, e2);
    // two ct-half dispatches: each streams only 2 MB of ehs (fits L2 w/ headroom);
    // A staged straight from x (k_split_x deleted)
    k_argmin<<<512, 256, 0, stream>>>(x, ehs, e2, idxw, carryV, carryI,
                                      out + OUT_IDX, counts, 0, 0);
    k_argmin<<<512, 256, 0, stream>>>(x, ehs, e2, idxw, carryV, carryI,
                                      out + OUT_IDX, counts, 8, 1);
    // counting-sort dw + fused quantized-output/loss (k_gather absorbed into k_dw)
    k_scan<<<1, 256, 0, stream>>>(counts, offs, woff);
    k_scatter<<<128, 256, 0, stream>>>(idxw, woff, rowlist);
    k_dw<<<4096, 256, 0, stream>>>(x, ehs, rowlist, offs, counts, dwT,
                                   out + OUT_Q, lossp);
    k_finalize<<<1, 256, 0, stream>>>(counts, lossp, ema_counter, ema_cluster,
                                      cnorm, scal, out);
    k_newemb<<<dim3(128, 8), 256, 0, stream>>>(dwT, ema_dw, cnorm, scal, out + OUT_EMB);
}

// Round 10
// 316.220 us; speedup vs baseline: 1.6293x; 1.0317x over previous
//
#include <hip/hip_runtime.h>
#include <math.h>

#define N_TOK 32768
#define DIM   256
#define KCODE 4096

// ---- workspace layout (float offsets) ----
#define WS_E2      0                      // [4096]
#define WS_COUNTS  4096                   // [4096]
#define WS_LOSSP   8192                   // [256]
#define WS_SCAL    8448                   // [64]  scal[0]=bias
#define WS_CNORM   8512                   // [4096]
#define WS_IDX     12608                  // int [32768]
#define WS_EHS     307520                 // fp16 planes [2][16][8][256][32] = 4 MB
#define WS_DWT     1356096                // dwT [4096*256]
#define WS_CARRYV  2404672                // float [32768] carry best value / later rowlist
#define WS_CARRYI  2437440                // int   [32768] carry best index
#define WS_OFFS    2470208                // int [4096] bucket starts
#define WS_WOFF    2474304                // int [4096] scatter cursors

// ---- output layout (float offsets) ----
#define OUT_Q      0
#define OUT_LOSS   8388608
#define OUT_PERP   8388609
#define OUT_IDX    8388610
#define OUT_EMB    8421378

#define EH_PLANE   1048576                // halves per eh plane

typedef _Float16 f16x8 __attribute__((ext_vector_type(8)));
typedef _Float16 f16x4 __attribute__((ext_vector_type(4)));
typedef float    f32x4 __attribute__((ext_vector_type(4)));

// emb [D][K] -> pre-tiled split planes ehs[p][ct][ks][code&255][d&31]
// ALSO accumulates e2[k] = sum_d emb[d][k]^2 (absorbs the old k_e2 kernel;
// e2 is memset-zeroed before this runs).
__global__ void k_split_e(const float* __restrict__ emb, unsigned short* __restrict__ ehs_,
                          float* __restrict__ e2)
{
    __shared__ float tile[32][33];
    _Float16* ehs = (_Float16*)ehs_;
    int t  = threadIdx.x;
    int tx = t & 31, iy = t >> 5;
    int k0 = blockIdx.x * 32, d0 = blockIdx.y * 32;
#pragma unroll
    for (int j = 0; j < 4; ++j)
        tile[iy + 8 * j][tx] = emb[(size_t)(d0 + iy + 8 * j) * KCODE + k0 + tx];
    __syncthreads();
    int code = k0 + tx;
    size_t base = (size_t)(((code >> 8) * 8) + (d0 >> 5)) * 8192 + (code & 255) * 32 + iy * 4;
    f16x4 h1, h2;
    float ssq = 0.0f;
#pragma unroll
    for (int j = 0; j < 4; ++j) {
        float v = tile[iy * 4 + j][tx];
        ssq += v * v;
        _Float16 a = (_Float16)v;
        h1[j] = a;
        h2[j] = (_Float16)(v - (float)a);
    }
    *(f16x4*)(ehs + base)            = h1;
    *(f16x4*)(ehs + EH_PLANE + base) = h2;
    atomicAdd(&e2[code], ssq);   // 64 adds per code total — trivial contention
}

// Argmin over codes via fp16x2-split MFMA, two ct-half dispatches (2 MB L2 WS each).
// This round's single schedule variable: s_setprio REMOVED. Theory: with 2
// waves/SIMD, prio-1 MFMA clusters starve the other wave's staging issue ->
// waves ping-pong serially (observed 44% MfmaUtil ~= 50% pipe idle). m190
// measured setprio as a regression on GEMM-like kernels.
// Also: per-ct e2 values are prefetched above the ks loop (kills the ~200cyc
// L2-latency stall the fold used to eat per ct).
__global__ __launch_bounds__(256, 2)
void k_argmin(const float* __restrict__ x, const unsigned short* __restrict__ ehs_,
              const float* __restrict__ e2, int* __restrict__ idx_out,
              float* __restrict__ carryV, int* __restrict__ carryI,
              float* __restrict__ out_idxf, float* __restrict__ counts,
              int ct0, int phase)
{
    __shared__ __align__(16) _Float16 Ah[2][64][256];   // 64 KB; XOR-swizzled 8-elem groups

    const _Float16* ehs = (const _Float16*)ehs_;

    const int t    = threadIdx.x;
    const int lane = t & 63, w = t >> 6;
    const int lo   = lane & 15, q = lane >> 4;
    const int row0 = blockIdx.x * 64;

    // ---- prologue: stage A planes from x with on-the-fly fp16 split ----
    {
        int m = t >> 3, kb = (t & 7) * 32;
#pragma unroll
        for (int rr = 0; rr < 2; ++rr) {
            int mm = m + 32 * rr;
            const float* src = x + (size_t)(row0 + mm) * DIM + kb;
#pragma unroll
            for (int g = 0; g < 4; ++g) {
                f32x4 f0 = __builtin_nontemporal_load((const f32x4*)(src + g * 8));
                f32x4 f1 = __builtin_nontemporal_load((const f32x4*)(src + g * 8 + 4));
                f16x8 h1, h2;
#pragma unroll
                for (int j = 0; j < 4; ++j) {
                    _Float16 a = (_Float16)f0[j];
                    h1[j] = a; h2[j] = (_Float16)(f0[j] - (float)a);
                    _Float16 b = (_Float16)f1[j];
                    h1[j + 4] = b; h2[j + 4] = (_Float16)(f1[j] - (float)b);
                }
                int grp = ((kb >> 3) + g) ^ (mm & 7);
                *(f16x8*)&Ah[0][mm][grp * 8] = h1;
                *(f16x8*)&Ah[1][mm][grp * 8] = h2;
            }
        }
    }
    __syncthreads();   // the ONLY barrier before the epilogue

    float best[16];
    int   bidx[16];
#pragma unroll
    for (int s = 0; s < 16; ++s) { best[s] = 3.4e38f; bidx[s] = 0; }

    // B fragment base: code-within-tile crow = w*64 + nf*16 + lo, d-off q*8
    const _Float16* ehp1 = ehs + (size_t)(w * 64 + lo) * 32 + q * 8;
    const _Float16* ehp2 = ehp1 + EH_PLANE;

    // register double-buffer for B fragments; parity = ks&1 (ks fully unrolled)
    f16x8 b1f[2][4], b2f[2][4];

    // prime: load B for so = ct0*8
    {
        const size_t so0 = (size_t)(ct0 * 8) * 8192;
#pragma unroll
        for (int nf = 0; nf < 4; ++nf) {
            b1f[0][nf] = *(const f16x8*)(ehp1 + so0 + nf * 512);
            b2f[0][nf] = *(const f16x8*)(ehp2 + so0 + nf * 512);
        }
    }

    for (int ct = ct0; ct < ct0 + 8; ++ct) {
        // prefetch this ct's e2 values (used only in the fold, 64 ks-steps away)
        float e2r[4];
#pragma unroll
        for (int nf = 0; nf < 4; ++nf)
            e2r[nf] = e2[ct * 256 + w * 64 + nf * 16 + lo];

        f32x4 acc[4][4];
#pragma unroll
        for (int mf = 0; mf < 4; ++mf)
#pragma unroll
            for (int nf = 0; nf < 4; ++nf) acc[mf][nf] = (f32x4)0.0f;

#pragma unroll
        for (int ks = 0; ks < 8; ++ks) {
            const int cur = ks & 1, nxt = cur ^ 1;
            const int so  = ct * 8 + ks;

            // ---- prefetch B for so+1 into the other parity buffer ----
            if (ks < 7 || ct < ct0 + 7) {
                const size_t po = (size_t)(so + 1) * 8192;
#pragma unroll
                for (int nf = 0; nf < 4; ++nf) {
                    b1f[nxt][nf] = *(const f16x8*)(ehp1 + po + nf * 512);
                    b2f[nxt][nf] = *(const f16x8*)(ehp2 + po + nf * 512);
                }
            }
            // pin the prefetch ahead of the MFMA cluster
            __builtin_amdgcn_sched_barrier(0);

            // ---- A fragments via LDS (conflict-free b128 via XOR swizzle) ----
            const int agrp = ((ks * 4 + q) ^ (lo & 7)) * 8;
            f16x8 a1[4], a2[4];
#pragma unroll
            for (int mf = 0; mf < 4; ++mf)
                a2[mf] = *(const f16x8*)&Ah[1][mf * 16 + lo][agrp];
#pragma unroll
            for (int mf = 0; mf < 4; ++mf)
                a1[mf] = *(const f16x8*)&Ah[0][mf * 16 + lo][agrp];

            // ---- MFMA cluster: per nf, product-major across mf (reuse dist 4) ----
            // (no setprio — this round's A/B variable)
#pragma unroll
            for (int nf = 0; nf < 4; ++nf) {
#pragma unroll
                for (int mf = 0; mf < 4; ++mf)
                    acc[mf][nf] = __builtin_amdgcn_mfma_f32_16x16x32_f16(a2[mf], b1f[cur][nf], acc[mf][nf], 0, 0, 0);
#pragma unroll
                for (int mf = 0; mf < 4; ++mf)
                    acc[mf][nf] = __builtin_amdgcn_mfma_f32_16x16x32_f16(a1[mf], b2f[cur][nf], acc[mf][nf], 0, 0, 0);
#pragma unroll
                for (int mf = 0; mf < 4; ++mf)
                    acc[mf][nf] = __builtin_amdgcn_mfma_f32_16x16x32_f16(a1[mf], b1f[cur][nf], acc[mf][nf], 0, 0, 0);
            }
        }

        // fold: dist = e2 - 2*score (x^2 row-constant dropped). codes ascending in ct,nf.
#pragma unroll
        for (int nf = 0; nf < 4; ++nf) {
            int cl = w * 64 + nf * 16 + lo;
            float e2v = e2r[nf];
#pragma unroll
            for (int mf = 0; mf < 4; ++mf)
#pragma unroll
                for (int r = 0; r < 4; ++r) {
                    float dist = fmaf(-2.0f, acc[mf][nf][r], e2v);
                    int s = mf * 4 + r;
                    if (dist < best[s]) { best[s] = dist; bidx[s] = ct * 256 + cl; }
                }
        }
    }

    // ---- final argmin reduction (scratch overlays Ah) ----
    __syncthreads();
    float* rv = (float*)&Ah[0][0][0];                 // [64 rows][64 slots]
    int*   ri = (int*)(((char*)&Ah[0][0][0]) + 16384);
#pragma unroll
    for (int s = 0; s < 16; ++s) {
        int row = (s >> 2) * 16 + q * 4 + (s & 3);    // mf*16 + q*4 + r
        rv[row * 64 + w * 16 + lo] = best[s];
        ri[row * 64 + w * 16 + lo] = bidx[s];
    }
    __syncthreads();
    if (t < 64) {
        float bv; int bi;
        if (phase) { bv = carryV[row0 + t]; bi = carryI[row0 + t]; }
        else       { bv = 3.4e38f; bi = 0x40000000; }
        // staggered scan start -> conflict-free
        for (int jj = 0; jj < 64; ++jj) {
            int j = (jj + t) & 63;
            float v = rv[t * 64 + j];
            int  ii = ri[t * 64 + j];
            if (v < bv || (v == bv && ii < bi)) { bv = v; bi = ii; }
        }
        if (phase) {
            idx_out[row0 + t] = bi;
            out_idxf[row0 + t] = (float)bi;
            atomicAdd(&counts[bi], 1.0f);
        } else {
            carryV[row0 + t] = bv; carryI[row0 + t] = bi;
        }
    }
}

// exclusive prefix sum over counts[4096] -> offs, woff (one block, 256 threads x 16)
__global__ void k_scan(const float* __restrict__ counts, int* __restrict__ offs,
                       int* __restrict__ woff)
{
    __shared__ int ps[256];
    int t = threadIdx.x;
    int local[16];
    int s = 0;
#pragma unroll
    for (int j = 0; j < 16; ++j) {
        local[j] = s;
        s += (int)counts[t * 16 + j];
    }
    ps[t] = s;
    __syncthreads();
    for (int off = 1; off < 256; off <<= 1) {
        int v = (t >= off) ? ps[t - off] : 0;
        __syncthreads();
        ps[t] += v;
        __syncthreads();
    }
    int base = (t > 0) ? ps[t - 1] : 0;
#pragma unroll
    for (int j = 0; j < 16; ++j) {
        int o = base + local[j];
        offs[t * 16 + j] = o;
        woff[t * 16 + j] = o;
    }
}

// rowlist[pos] = n, grouped by code (counting-sort scatter)
__global__ void k_scatter(const int* __restrict__ idx, int* __restrict__ woff,
                          int* __restrict__ rowlist)
{
    int n = blockIdx.x * 256 + threadIdx.x;
    int k = idx[n];
    int pos = atomicAdd(&woff[k], 1);
    rowlist[pos] = n;
}

// Per-code fused update: one block per code k.
//   dwT[k][:]  = sum of x rows in bucket k          (atomic-free)
//   out_q[n,:] = e_k  for every row n in bucket     (absorbs old k_gather)
//   lossp     += cnt*|e|^2 - 2*e.dw + sum|x|^2      (algebraic bucket loss)
__global__ void k_dw(const float* __restrict__ x, const unsigned short* __restrict__ ehs_,
                     const int* __restrict__ rowlist, const int* __restrict__ offs,
                     const float* __restrict__ counts, float* __restrict__ dwT,
                     float* __restrict__ out_q, float* __restrict__ lossp)
{
    __shared__ __align__(16) float es[256];
    __shared__ __align__(16) float red[4][256];
    const _Float16* ehs = (const _Float16*)ehs_;
    int k = blockIdx.x, t = threadIdx.x;
    int lane = t & 63, w = t >> 6;
    // reconstruct e_k: thread t -> dimension d = t
    size_t base = (size_t)(((k >> 8) * 8) + (t >> 5)) * 8192 + (k & 255) * 32 + (t & 31);
    float e = (float)ehs[base] + (float)ehs[EH_PLANE + base];
    es[t] = e;
    int start = offs[k];
    int cnt   = (int)counts[k];
    __syncthreads();
    float4 ev = *(const float4*)&es[lane * 4];
    float4 acc = {0.0f, 0.0f, 0.0f, 0.0f};
    float sq = 0.0f;
    for (int j = w; j < cnt; j += 4) {
        int n = rowlist[start + j];
        float4 xv = *(const float4*)&x[(size_t)n * DIM + lane * 4];
        acc.x += xv.x; acc.y += xv.y; acc.z += xv.z; acc.w += xv.w;
        sq += xv.x * xv.x + xv.y * xv.y + xv.z * xv.z + xv.w * xv.w;
        *(float4*)&out_q[(size_t)n * DIM + lane * 4] = ev;
    }
    *(float4*)&red[w][lane * 4] = acc;
    __syncthreads();
    float s = red[0][t] + red[1][t] + red[2][t] + red[3][t];
    dwT[(size_t)k * DIM + t] = s;
    // bucket loss reduction: dot(e,dw), |e|^2, sum|x|^2
    float v1 = es[t] * s;     // dot partial (each t = unique d)
    float v2 = e * e;         // |e|^2 partial
    float v3 = sq;            // sum x^2 partial
#pragma unroll
    for (int off = 32; off > 0; off >>= 1) {
        v1 += __shfl_down(v1, off, 64);
        v2 += __shfl_down(v2, off, 64);
        v3 += __shfl_down(v3, off, 64);
    }
    __syncthreads();
    if (lane == 0) { red[0][w] = v1; red[1][w] = v2; red[2][w] = v3; }
    __syncthreads();
    if (t == 0 && cnt > 0) {
        float dot = red[0][0] + red[0][1] + red[0][2] + red[0][3];
        float e2t = red[1][0] + red[1][1] + red[1][2] + red[1][3];
        float sqt = red[2][0] + red[2][1] + red[2][2] + red[2][3];
        atomicAdd(&lossp[k & 255], (float)cnt * e2t - 2.0f * dot + sqt);
    }
}

__global__ void k_finalize(const float* __restrict__ counts, const float* __restrict__ lossp,
                           const float* __restrict__ ema_counter,
                           const float* __restrict__ ema_cluster,
                           float* __restrict__ cnorm, float* __restrict__ scal,
                           float* __restrict__ out)
{
    __shared__ float red[256];
    int t = threadIdx.x;
    float ls = lossp[t];
    float ent = 0.0f, casum = 0.0f;
    float ca[16];
#pragma unroll
    for (int j = 0; j < 16; ++j) {
        int k = j * 256 + t;
        float c = counts[k];
        float p = c * (1.0f / 32768.0f);
        ent += p * logf(p + 1e-10f);
        ca[j] = ema_cluster[k] * 0.99f + c * 0.01f;   // cluster_hidden
        casum += ca[j];
    }
    red[t] = ls; __syncthreads();
    for (int o = 128; o > 0; o >>= 1) { if (t < o) red[t] += red[t + o]; __syncthreads(); }
    float loss_tot = red[0]; __syncthreads();
    red[t] = ent; __syncthreads();
    for (int o = 128; o > 0; o >>= 1) { if (t < o) red[t] += red[t + o]; __syncthreads(); }
    float ent_tot = red[0]; __syncthreads();
    red[t] = casum; __syncthreads();
    for (int o = 128; o > 0; o >>= 1) { if (t < o) red[t] += red[t + o]; __syncthreads(); }
    float casum_tot = red[0]; __syncthreads();

    float bias = 1.0f - powf(0.99f, ema_counter[0] + 1.0f);
    float n = casum_tot / bias;                 // sum(cluster_avg)
    float inv = n / (n + 4096.0f * 1e-5f);
#pragma unroll
    for (int j = 0; j < 16; ++j) {
        int k = j * 256 + t;
        cnorm[k] = (ca[j] / bias + 1e-5f) * inv;
    }
    if (t == 0) {
        out[OUT_LOSS] = 1.25f * loss_tot * (1.0f / (32768.0f * 256.0f));
        out[OUT_PERP] = expf(-ent_tot);
        scal[0] = bias;
    }
}

// new_embeddings[d][k] = (ema_dw*DECAY + dwT^T*(1-DECAY))/bias / cnorm[k]
__global__ void k_newemb(const float* __restrict__ dwT, const float* __restrict__ ema_dw,
                         const float* __restrict__ cnorm, const float* __restrict__ scal,
                         float* __restrict__ out_emb)
{
    __shared__ float tile[32][33];
    int t = threadIdx.x;
    int tx = t & 31, iy = t >> 5;
    int k0 = blockIdx.x * 32, d0 = blockIdx.y * 32;
#pragma unroll
    for (int j = 0; j < 4; ++j)
        tile[iy + 8 * j][tx] = dwT[(size_t)(k0 + iy + 8 * j) * DIM + d0 + tx];
    __syncthreads();
    float inv_bias = 1.0f / scal[0];
    float cn = cnorm[k0 + tx];
#pragma unroll
    for (int j = 0; j < 4; ++j) {
        int d = d0 + iy + 8 * j;
        float dwv = tile[tx][iy + 8 * j];
        float hid = ema_dw[(size_t)d * KCODE + k0 + tx] * 0.99f + dwv * 0.01f;
        out_emb[(size_t)d * KCODE + k0 + tx] = hid * inv_bias / cn;
    }
}

extern "C" void kernel_launch(void* const* d_in, const int* in_sizes, int n_in,
                              void* d_out, int out_size, void* d_ws, size_t ws_size,
                              hipStream_t stream)
{
    const float* x           = (const float*)d_in[0];
    const float* emb         = (const float*)d_in[1];
    const float* ema_counter = (const float*)d_in[2];
    const float* ema_cluster = (const float*)d_in[3];
    const float* ema_dw      = (const float*)d_in[4];
    float* out = (float*)d_out;
    float* ws  = (float*)d_ws;

    float* e2     = ws + WS_E2;
    float* counts = ws + WS_COUNTS;
    float* lossp  = ws + WS_LOSSP;
    float* scal   = ws + WS_SCAL;
    float* cnorm  = ws + WS_CNORM;
    int*   idxw   = (int*)(ws + WS_IDX);
    unsigned short* ehs = (unsigned short*)(ws + WS_EHS);
    float* dwT    = ws + WS_DWT;
    float* carryV = ws + WS_CARRYV;
    int*   carryI = (int*)(ws + WS_CARRYI);
    int*   rowlist= (int*)(ws + WS_CARRYV);   // overlays carryV (dead after argmin B)
    int*   offs   = (int*)(ws + WS_OFFS);
    int*   woff   = (int*)(ws + WS_WOFF);

    hipMemsetAsync(e2, 0, (size_t)WS_CNORM * sizeof(float), stream);  // zeros e2+counts+lossp+scal

    // emb -> split planes + e2 (k_e2 absorbed)
    k_split_e<<<dim3(128, 8), 256, 0, stream>>>(emb, ehs, e2);
    // two ct-half dispatches: each streams only 2 MB of ehs (fits L2 w/ headroom);
    // A staged straight from x (k_split_x deleted)
    k_argmin<<<512, 256, 0, stream>>>(x, ehs, e2, idxw, carryV, carryI,
                                      out + OUT_IDX, counts, 0, 0);
    k_argmin<<<512, 256, 0, stream>>>(x, ehs, e2, idxw, carryV, carryI,
                                      out + OUT_IDX, counts, 8, 1);
    // counting-sort dw + fused quantized-output/loss (k_gather absorbed into k_dw)
    k_scan<<<1, 256, 0, stream>>>(counts, offs, woff);
    k_scatter<<<128, 256, 0, stream>>>(idxw, woff, rowlist);
    k_dw<<<4096, 256, 0, stream>>>(x, ehs, rowlist, offs, counts, dwT,
                                   out + OUT_Q, lossp);
    k_finalize<<<1, 256, 0, stream>>>(counts, lossp, ema_counter, ema_cluster,
                                      cnorm, scal, out);
    k_newemb<<<dim3(128, 8), 256, 0, stream>>>(dwT, ema_dw, cnorm, scal, out + OUT_EMB);
}